// Round 1
// baseline (446.426 us; speedup 1.0000x reference)
//
#include <hip/hip_runtime.h>

// GCN 3-layer (PyG GCNConv semantics: self-loops + D^-1/2 A D^-1/2 norm).
// Strategy: build CSR-by-dst per call, store hw pre-scaled by dinv[src],
// aggregate wave-per-node (lane = feature), fuse next layer's dense GEMM
// into the aggregation kernel via LDS float4 broadcast + W column in VGPRs.

__global__ void k_count(const int* __restrict__ dst, int E, int* __restrict__ deg) {
    int e = blockIdx.x * blockDim.x + threadIdx.x;
    if (e < E) atomicAdd(&deg[dst[e]], 1);
}

// Block-local exclusive scan (256 elems/block) -> rowptr partial + block sums
__global__ void k_scan1(const int* __restrict__ deg, int N,
                        int* __restrict__ rowptr, int* __restrict__ bsum) {
    __shared__ int lds[256];
    int t = threadIdx.x;
    int i = blockIdx.x * 256 + t;
    int v = (i < N) ? deg[i] : 0;
    lds[t] = v; __syncthreads();
    #pragma unroll
    for (int off = 1; off < 256; off <<= 1) {
        int tmp = (t >= off) ? lds[t - off] : 0; __syncthreads();
        lds[t] += tmp; __syncthreads();
    }
    if (i < N) rowptr[i] = lds[t] - v;          // exclusive within block
    if (t == 255) bsum[blockIdx.x] = lds[255];  // block total
}

// Single-block exclusive scan of block sums (supports nb <= 1024)
__global__ void k_scan2(const int* __restrict__ bsum, int nb, int* __restrict__ boff) {
    __shared__ int lds[1024];
    int t = threadIdx.x;
    int v = (t < nb) ? bsum[t] : 0;
    lds[t] = v; __syncthreads();
    #pragma unroll
    for (int off = 1; off < 1024; off <<= 1) {
        int tmp = (t >= off) ? lds[t - off] : 0; __syncthreads();
        lds[t] += tmp; __syncthreads();
    }
    if (t < nb) boff[t] = lds[t] - v;
    if (t == 0) boff[nb] = lds[1023];           // grand total = E
}

// Add block offsets; compute dinv = rsqrt(in_deg + 1); zero deg (reuse as cursor)
__global__ void k_scan3(const int* __restrict__ boff, int N, int nb,
                        int* __restrict__ rowptr, int* __restrict__ deg,
                        float* __restrict__ dinv) {
    int i = blockIdx.x * blockDim.x + threadIdx.x;
    if (i < N) {
        rowptr[i] += boff[i >> 8];
        dinv[i] = rsqrtf((float)deg[i] + 1.0f);
        deg[i] = 0;
    } else if (i == N) {
        rowptr[N] = boff[nb];
    }
}

__global__ void k_fill(const int* __restrict__ src, const int* __restrict__ dst, int E,
                       const int* __restrict__ rowptr, int* __restrict__ cursor,
                       int* __restrict__ col) {
    int e = blockIdx.x * blockDim.x + threadIdx.x;
    if (e < E) {
        int d = dst[e];
        int p = atomicAdd(&cursor[d], 1);
        col[rowptr[d] + p] = src[e];
    }
}

// Layer-1 GEMM collapses: h = [x, delta...] -> hw1[n,d] = x[n]*W1[0,d] + c[d];
// store pre-scaled by dinv[n].
__global__ void k_layer1(const float* __restrict__ x, const float* __restrict__ delta,
                         const float* __restrict__ W1, const float* __restrict__ dinv,
                         float* __restrict__ hw, int N) {
    int idx = blockIdx.x * blockDim.x + threadIdx.x;
    if (idx >= N * 64) return;
    int n = idx >> 6, d = idx & 63;
    float c = delta[0] * W1[64 + d] + delta[1] * W1[128 + d] +
              delta[2] * W1[192 + d] + delta[3] * W1[256 + d];
    hw[idx] = dinv[n] * fmaf(x[n], W1[d], c);
}

// Wave-per-node aggregation: lane = feature d. Coalesced 256B row per edge.
__device__ __forceinline__ float agg_row(const float* __restrict__ hw_in,
                                         const int* __restrict__ col,
                                         int rs, int re, int lane, float self) {
    float acc = self;
    for (int base = rs; base < re; base += 64) {
        int cnt = min(64, re - base);
        int s = (lane < cnt) ? col[base + lane] : 0;  // coalesced index load
        int j = 0;
        for (; j + 4 <= cnt; j += 4) {               // 4 gathers in flight
            int s0 = __shfl(s, j), s1 = __shfl(s, j + 1);
            int s2 = __shfl(s, j + 2), s3 = __shfl(s, j + 3);
            float v0 = hw_in[(size_t)s0 * 64 + lane];
            float v1 = hw_in[(size_t)s1 * 64 + lane];
            float v2 = hw_in[(size_t)s2 * 64 + lane];
            float v3 = hw_in[(size_t)s3 * 64 + lane];
            acc += (v0 + v1) + (v2 + v3);
        }
        for (; j < cnt; ++j)
            acc += hw_in[(size_t)__shfl(s, j) * 64 + lane];
    }
    return acc;
}

// agg(prev layer) -> relu(dinv*acc + b) -> GEMM with 64x64 W -> store dinv-scaled
__global__ __launch_bounds__(256) void k_agg_gemm64(
    const float* __restrict__ hw_in, const int* __restrict__ rowptr,
    const int* __restrict__ col, const float* __restrict__ dinv,
    const float* __restrict__ bias, const float* __restrict__ W,
    float* __restrict__ hw_out, int N) {
    __shared__ float rowbuf[4][64];
    int lane = threadIdx.x & 63, wave = threadIdx.x >> 6;
    float Wreg[64];                       // column `lane` of W in VGPRs
    #pragma unroll
    for (int k = 0; k < 64; ++k) Wreg[k] = W[k * 64 + lane];
    float b = bias[lane];
    int gw = blockIdx.x * 4 + wave;
    int stride = gridDim.x * 4;
    for (int n = gw; n < N; n += stride) {
        float self = hw_in[(size_t)n * 64 + lane];
        int rs = rowptr[n], re = rowptr[n + 1];
        float acc = agg_row(hw_in, col, rs, re, lane, self);
        float dn = dinv[n];
        float t = fmaxf(fmaf(dn, acc, b), 0.0f);
        rowbuf[wave][lane] = t;           // wave-private row, no block barrier needed
        __builtin_amdgcn_wave_barrier();
        float o = 0.f;
        const float4* rb = (const float4*)(&rowbuf[wave][0]);
        #pragma unroll
        for (int k4 = 0; k4 < 16; ++k4) { // 16 broadcast ds_read_b128 per node
            float4 tv = rb[k4];
            o = fmaf(tv.x, Wreg[4 * k4 + 0], o);
            o = fmaf(tv.y, Wreg[4 * k4 + 1], o);
            o = fmaf(tv.z, Wreg[4 * k4 + 2], o);
            o = fmaf(tv.w, Wreg[4 * k4 + 3], o);
        }
        hw_out[(size_t)n * 64 + lane] = dn * o;
    }
}

// agg(layer2) -> relu -> GEMM with W3 (64x3) via butterfly reduce -> hw3 (float4-padded)
__global__ __launch_bounds__(256) void k_agg_out3(
    const float* __restrict__ hw_in, const int* __restrict__ rowptr,
    const int* __restrict__ col, const float* __restrict__ dinv,
    const float* __restrict__ bias, const float* __restrict__ W3,
    float4* __restrict__ hw3, int N) {
    int lane = threadIdx.x & 63, wave = threadIdx.x >> 6;
    float w0 = W3[lane * 3 + 0], w1 = W3[lane * 3 + 1], w2 = W3[lane * 3 + 2];
    float b = bias[lane];
    int gw = blockIdx.x * 4 + wave;
    int stride = gridDim.x * 4;
    for (int n = gw; n < N; n += stride) {
        float self = hw_in[(size_t)n * 64 + lane];
        int rs = rowptr[n], re = rowptr[n + 1];
        float acc = agg_row(hw_in, col, rs, re, lane, self);
        float dn = dinv[n];
        float t = fmaxf(fmaf(dn, acc, b), 0.0f);
        float p0 = t * w0, p1 = t * w1, p2 = t * w2;
        #pragma unroll
        for (int off = 32; off; off >>= 1) {
            p0 += __shfl_xor(p0, off);
            p1 += __shfl_xor(p1, off);
            p2 += __shfl_xor(p2, off);
        }
        if (lane == 0) hw3[n] = make_float4(dn * p0, dn * p1, dn * p2, 0.f);
    }
}

// Final 3-wide aggregation + residual outputs. out = [new_type (N), new_pos (2N)]
__global__ __launch_bounds__(256) void k_final(
    const float4* __restrict__ hw3, const int* __restrict__ rowptr,
    const int* __restrict__ col, const float* __restrict__ dinv,
    const float* __restrict__ b3, const float* __restrict__ x,
    const float* __restrict__ pos, float* __restrict__ out, int N) {
    int lane = threadIdx.x & 63, wave = threadIdx.x >> 6;
    int n = blockIdx.x * 4 + wave;
    if (n >= N) return;
    int rs = rowptr[n], re = rowptr[n + 1];
    float a0 = 0.f, a1 = 0.f, a2 = 0.f;
    for (int i = rs + lane; i < re; i += 64) {
        float4 v = hw3[col[i]];
        a0 += v.x; a1 += v.y; a2 += v.z;
    }
    #pragma unroll
    for (int off = 32; off; off >>= 1) {
        a0 += __shfl_xor(a0, off);
        a1 += __shfl_xor(a1, off);
        a2 += __shfl_xor(a2, off);
    }
    if (lane == 0) {
        float4 sv = hw3[n];                 // self-loop
        a0 += sv.x; a1 += sv.y; a2 += sv.z;
        float dn = dinv[n];
        float o0 = fmaf(dn, a0, b3[0]);
        float o1 = fmaf(dn, a1, b3[1]);
        float o2 = fmaf(dn, a2, b3[2]);
        out[n] = x[n] + o2;                 // new_type
        out[N + 2 * n]     = pos[2 * n]     + o0;  // new_pos.x
        out[N + 2 * n + 1] = pos[2 * n + 1] + o1;  // new_pos.y
    }
}

extern "C" void kernel_launch(void* const* d_in, const int* in_sizes, int n_in,
                              void* d_out, int out_size, void* d_ws, size_t ws_size,
                              hipStream_t stream) {
    const float* x     = (const float*)d_in[0];
    const float* pos   = (const float*)d_in[1];
    const float* delta = (const float*)d_in[2];
    const int*   ei    = (const int*)  d_in[3];
    const float* W1    = (const float*)d_in[4];
    const float* b1    = (const float*)d_in[5];
    const float* W2    = (const float*)d_in[6];
    const float* b2    = (const float*)d_in[7];
    const float* W3    = (const float*)d_in[8];
    const float* b3    = (const float*)d_in[9];
    int N = in_sizes[0];
    int E = in_sizes[3] / 2;
    const int* src = ei;
    const int* dst = ei + E;

    // workspace bump allocator (256B aligned)
    char* p = (char*)d_ws;
    auto alloc = [&](size_t bytes) {
        char* r = p; p += (bytes + 255) & ~(size_t)255; return r;
    };
    int*   deg    = (int*)  alloc((size_t)N * 4);        // then reused as cursor
    int*   rowptr = (int*)  alloc((size_t)(N + 1) * 4);
    int nb1 = (N + 255) / 256;
    int*   bsum   = (int*)  alloc((size_t)nb1 * 4);
    int*   boff   = (int*)  alloc((size_t)(nb1 + 1) * 4);
    float* dinv   = (float*)alloc((size_t)N * 4);
    int*   col    = (int*)  alloc((size_t)E * 4);
    float* hw_a   = (float*)alloc((size_t)N * 64 * 4);
    float* hw_b   = (float*)alloc((size_t)N * 64 * 4);
    float4* hw3   = (float4*)hw_a;                        // reuse: hw_a dead after layer2

    hipMemsetAsync(deg, 0, (size_t)N * 4, stream);
    k_count<<<(E + 255) / 256, 256, 0, stream>>>(dst, E, deg);
    k_scan1<<<nb1, 256, 0, stream>>>(deg, N, rowptr, bsum);
    k_scan2<<<1, 1024, 0, stream>>>(bsum, nb1, boff);
    k_scan3<<<(N + 256) / 256, 256, 0, stream>>>(boff, N, nb1, rowptr, deg, dinv);
    k_fill<<<(E + 255) / 256, 256, 0, stream>>>(src, dst, E, rowptr, deg, col);
    k_layer1<<<(N * 64 + 255) / 256, 256, 0, stream>>>(x, delta, W1, dinv, hw_a, N);
    k_agg_gemm64<<<2048, 256, 0, stream>>>(hw_a, rowptr, col, dinv, b1, W2, hw_b, N);
    k_agg_out3<<<2048, 256, 0, stream>>>(hw_b, rowptr, col, dinv, b2, W3, hw3, N);
    k_final<<<(N + 3) / 4, 256, 0, stream>>>(hw3, rowptr, col, dinv, b3, x, pos,
                                             (float*)d_out, N);
}